// Round 2
// baseline (13742.380 us; speedup 1.0000x reference)
//
#include <hip/hip_runtime.h>
#include <stdint.h>

// PointNet EdgeConv, 2 layers. Round 2: atomic-scatter-max was the bottleneck
// (51.2M atomics/layer -> 1.6 GB memory-side write traffic, 24.5 G atomics/s).
// New plan: counting-sort edges by dst into CSR once, then gather-per-node:
// each node-thread recomputes the per-edge MLP (weights in LDS) and keeps a
// running 32-channel max in registers. Zero aggregation atomics.

#define N_HIDDEN 32
#define BS 256

// ---------------- counting sort (CSR build) ----------------

__global__ __launch_bounds__(BS) void zero_kernel(int* __restrict__ p, int n) {
    int i = blockIdx.x * BS + threadIdx.x;
    if (i < n) p[i] = 0;
}

__global__ __launch_bounds__(BS) void hist_kernel(const int* __restrict__ ei, int E,
                                                  int* __restrict__ cnt) {
    int e = blockIdx.x * BS + threadIdx.x;
    if (e < E) atomicAdd(&cnt[ei[E + e]], 1);
}

// per-block reduce of cnt -> bsum[block]
__global__ __launch_bounds__(BS) void bsum_kernel(const int* __restrict__ cnt, int n,
                                                  int* __restrict__ bsum) {
    __shared__ int s[BS];
    int t = threadIdx.x;
    int i = blockIdx.x * BS + t;
    s[t] = (i < n) ? cnt[i] : 0;
    __syncthreads();
    for (int st = BS / 2; st > 0; st >>= 1) {
        if (t < st) s[t] += s[t + st];
        __syncthreads();
    }
    if (t == 0) bsum[blockIdx.x] = s[0];
}

// single-block exclusive scan of bsum[0..nb) -> bpre  (nb <= 512)
__global__ __launch_bounds__(512) void bscan_kernel(const int* __restrict__ bsum, int nb,
                                                    int* __restrict__ bpre) {
    __shared__ int s[512];
    int t = threadIdx.x;
    int v = (t < nb) ? bsum[t] : 0;
    s[t] = v;
    __syncthreads();
    for (int off = 1; off < 512; off <<= 1) {
        int add = (t >= off) ? s[t - off] : 0;
        __syncthreads();
        s[t] += add;
        __syncthreads();
    }
    if (t < nb) bpre[t] = s[t] - v;  // exclusive
}

// per-block exclusive scan + block prefix -> row_ptr, cursor
__global__ __launch_bounds__(BS) void scan_kernel(const int* __restrict__ cnt, int n,
                                                  const int* __restrict__ bpre,
                                                  int* __restrict__ row_ptr,
                                                  int* __restrict__ cursor) {
    __shared__ int s[BS];
    int t = threadIdx.x;
    int i = blockIdx.x * BS + t;
    int v = (i < n) ? cnt[i] : 0;
    s[t] = v;
    __syncthreads();
    for (int off = 1; off < BS; off <<= 1) {
        int add = (t >= off) ? s[t - off] : 0;
        __syncthreads();
        s[t] += add;
        __syncthreads();
    }
    if (i < n) {
        int r = bpre[blockIdx.x] + s[t] - v;
        row_ptr[i] = r;
        cursor[i] = r;
    }
}

__global__ __launch_bounds__(BS) void scatter_kernel(const int* __restrict__ ei, int E,
                                                     int* __restrict__ cursor,
                                                     int* __restrict__ ssrc) {
    int e = blockIdx.x * BS + threadIdx.x;
    if (e < E) {
        int p = atomicAdd(&cursor[ei[E + e]], 1);
        ssrc[p] = ei[e];
    }
}

// ---------------- fused gather-max layer ----------------
// One thread per node n: for each incoming edge (sorted CSR), recompute
//   m = relu(concat(feat_src, pos_src - pos_n) @ Wa + ba) @ Wb + bb
// and keep running max. Output = fmaxf(max, 0)  (relu; also maps deg==0 -> 0).
// IN_DIM = 6 (layer 1) or 35 (layer 2, hfeat = h1).

template <int IN_DIM>
__global__ __launch_bounds__(64) void gather_kernel(
    const float* __restrict__ pos, const int* __restrict__ row_ptr, const int* __restrict__ cnt,
    const int* __restrict__ ssrc, const float* __restrict__ hfeat, const float* __restrict__ Wa,
    const float* __restrict__ ba, const float* __restrict__ Wb, const float* __restrict__ bb,
    float* __restrict__ out, int N) {
    __shared__ float sWa[IN_DIM * 32];
    __shared__ float sba[32];
    __shared__ float sWb[32 * 32];
    __shared__ float sbb[32];

    const int tid = threadIdx.x;
    for (int i = tid; i < IN_DIM * 32; i += 64) sWa[i] = Wa[i];
    for (int i = tid; i < 32 * 32; i += 64) sWb[i] = Wb[i];
    if (tid < 32) {
        sba[tid] = ba[tid];
        sbb[tid] = bb[tid];
    }
    __syncthreads();

    const int n = blockIdx.x * 64 + tid;
    if (n >= N) return;

    const int start = row_ptr[n];
    const int deg = cnt[n];
    const float pdx = pos[n * 3 + 0];
    const float pdy = pos[n * 3 + 1];
    const float pdz = pos[n * 3 + 2];

    float acc[32];
#pragma unroll
    for (int c = 0; c < 32; ++c) acc[c] = -INFINITY;

    for (int k = 0; k < deg; ++k) {
        const int s = ssrc[start + k];
        const float psx = pos[s * 3 + 0];
        const float psy = pos[s * 3 + 1];
        const float psz = pos[s * 3 + 2];

        float feat[IN_DIM];
        if constexpr (IN_DIM == 6) {
            feat[0] = psx;
            feat[1] = psy;
            feat[2] = psz;
            feat[3] = psx - pdx;
            feat[4] = psy - pdy;
            feat[5] = psz - pdz;
        } else {
            const float4* hp = reinterpret_cast<const float4*>(hfeat + (size_t)s * 32);
#pragma unroll
            for (int q = 0; q < 8; ++q) {
                float4 v = hp[q];
                feat[q * 4 + 0] = v.x;
                feat[q * 4 + 1] = v.y;
                feat[q * 4 + 2] = v.z;
                feat[q * 4 + 3] = v.w;
            }
            feat[32] = psx - pdx;
            feat[33] = psy - pdy;
            feat[34] = psz - pdz;
        }

        // hidden = relu(feat @ Wa + ba)
        float hid[32];
#pragma unroll
        for (int f4 = 0; f4 < 8; ++f4) {
            float4 a = *reinterpret_cast<const float4*>(&sba[f4 * 4]);
#pragma unroll
            for (int i = 0; i < IN_DIM; ++i) {
                float4 w = *reinterpret_cast<const float4*>(&sWa[i * 32 + f4 * 4]);
                a.x = fmaf(feat[i], w.x, a.x);
                a.y = fmaf(feat[i], w.y, a.y);
                a.z = fmaf(feat[i], w.z, a.z);
                a.w = fmaf(feat[i], w.w, a.w);
            }
            hid[f4 * 4 + 0] = fmaxf(a.x, 0.0f);
            hid[f4 * 4 + 1] = fmaxf(a.y, 0.0f);
            hid[f4 * 4 + 2] = fmaxf(a.z, 0.0f);
            hid[f4 * 4 + 3] = fmaxf(a.w, 0.0f);
        }

        // m = hidden @ Wb + bb ; running max
#pragma unroll
        for (int k4 = 0; k4 < 8; ++k4) {
            float4 a = *reinterpret_cast<const float4*>(&sbb[k4 * 4]);
#pragma unroll
            for (int h = 0; h < 32; ++h) {
                float4 w = *reinterpret_cast<const float4*>(&sWb[h * 32 + k4 * 4]);
                a.x = fmaf(hid[h], w.x, a.x);
                a.y = fmaf(hid[h], w.y, a.y);
                a.z = fmaf(hid[h], w.z, a.z);
                a.w = fmaf(hid[h], w.w, a.w);
            }
            acc[k4 * 4 + 0] = fmaxf(acc[k4 * 4 + 0], a.x);
            acc[k4 * 4 + 1] = fmaxf(acc[k4 * 4 + 1], a.y);
            acc[k4 * 4 + 2] = fmaxf(acc[k4 * 4 + 2], a.z);
            acc[k4 * 4 + 3] = fmaxf(acc[k4 * 4 + 3], a.w);
        }
    }

    float4* op = reinterpret_cast<float4*>(out + (size_t)n * 32);
#pragma unroll
    for (int q = 0; q < 8; ++q) {
        float4 v;
        v.x = fmaxf(acc[q * 4 + 0], 0.0f);
        v.y = fmaxf(acc[q * 4 + 1], 0.0f);
        v.z = fmaxf(acc[q * 4 + 2], 0.0f);
        v.w = fmaxf(acc[q * 4 + 3], 0.0f);
        op[q] = v;
    }
}

extern "C" void kernel_launch(void* const* d_in, const int* in_sizes, int n_in,
                              void* d_out, int out_size, void* d_ws, size_t ws_size,
                              hipStream_t stream) {
    const float* pos = (const float*)d_in[0];
    const int* ei = (const int*)d_in[1];
    const float* W1 = (const float*)d_in[3];
    const float* b1 = (const float*)d_in[4];
    const float* W2 = (const float*)d_in[5];
    const float* b2 = (const float*)d_in[6];
    const float* W3 = (const float*)d_in[7];
    const float* b3 = (const float*)d_in[8];
    const float* W4 = (const float*)d_in[9];
    const float* b4 = (const float*)d_in[10];

    const int E = in_sizes[1] / 2;
    const int N = in_sizes[0] / 3;
    const int NPAD = ((N + BS - 1) / BS) * BS;
    const int NB = (N + BS - 1) / BS;  // blocks over nodes (<= 512 required)
    const int EB = (E + BS - 1) / BS;

    int* cnt = (int*)d_ws;        // NPAD
    int* row_ptr = cnt + NPAD;    // NPAD
    int* cursor = row_ptr + NPAD; // NPAD
    int* bsum = cursor + NPAD;    // 512
    int* bpre = bsum + 512;       // 512
    int* ssrc = bpre + 512;       // E
    float* h1 = (float*)(ssrc + E);  // N*32 (16B-aligned: all offsets are x4 ints, E mult of 4)

    // --- CSR build (once, shared by both layers) ---
    zero_kernel<<<NB, BS, 0, stream>>>(cnt, N);
    hist_kernel<<<EB, BS, 0, stream>>>(ei, E, cnt);
    bsum_kernel<<<NB, BS, 0, stream>>>(cnt, N, bsum);
    bscan_kernel<<<1, 512, 0, stream>>>(bsum, NB, bpre);
    scan_kernel<<<NB, BS, 0, stream>>>(cnt, N, bpre, row_ptr, cursor);
    scatter_kernel<<<EB, BS, 0, stream>>>(ei, E, cursor, ssrc);

    // --- layers ---
    const int GN = (N + 63) / 64;
    gather_kernel<6><<<GN, 64, 0, stream>>>(pos, row_ptr, cnt, ssrc, nullptr, W1, b1, W2, b2,
                                            h1, N);
    gather_kernel<35><<<GN, 64, 0, stream>>>(pos, row_ptr, cnt, ssrc, h1, W3, b3, W4, b4,
                                             (float*)d_out, N);
}

// Round 3
// 645.618 us; speedup vs baseline: 21.2856x; 21.2856x over previous
//
#include <hip/hip_runtime.h>
#include <stdint.h>

// PointNet EdgeConv, 2 layers. Round 3.
// R1: thread-per-edge MLP healthy (40 VGPR) but 51.2M scatter atomics -> 1.6 GB
//     memory-side writes, atomic-throughput-bound (2.1 ms/layer).
// R2: thread-per-node gather spilled (VGPR=256, 9.6 GB scratch fetch) -> 9.9 ms.
// R3: counting-sort edges by dst (CSR), then thread-per-edge MLP + BLOCK-LOCAL
//     segmented max in LDS. Sorted => each 256-edge block covers ~16 contiguous
//     nodes; interior nodes: one plain store; straddling nodes: ordered-uint
//     atomicMax (~400K atomics/layer, 128x fewer than R1).

#define BS 256

__device__ __forceinline__ unsigned ordenc(float f) {
    unsigned u = __float_as_uint(f);
    return (u & 0x80000000u) ? ~u : (u | 0x80000000u);
}
__device__ __forceinline__ float orddec(unsigned o) {
    unsigned u = (o & 0x80000000u) ? (o ^ 0x80000000u) : ~o;
    return __uint_as_float(u);
}
#define ORD_NEG_INF 0x007FFFFFu  // ordenc(-inf)

// ---------------- small utility kernels ----------------

__global__ __launch_bounds__(BS) void init_agg_kernel(unsigned* __restrict__ a,
                                                      unsigned* __restrict__ b, int n) {
    int i = blockIdx.x * BS + threadIdx.x;
    if (i < n) {
        a[i] = ORD_NEG_INF;
        b[i] = ORD_NEG_INF;
    }
}

// decode ordered max in place + relu (maps -inf from deg-0 nodes to 0)
__global__ __launch_bounds__(BS) void finalize_kernel(unsigned* __restrict__ buf, int n) {
    int i = blockIdx.x * BS + threadIdx.x;
    if (i < n) {
        float v = orddec(buf[i]);
        reinterpret_cast<float*>(buf)[i] = fmaxf(v, 0.0f);
    }
}

// ---------------- counting sort (CSR build) ----------------

__global__ __launch_bounds__(BS) void zero_kernel(int* __restrict__ p, int n) {
    int i = blockIdx.x * BS + threadIdx.x;
    if (i < n) p[i] = 0;
}

__global__ __launch_bounds__(BS) void hist_kernel(const int* __restrict__ ei, int E,
                                                  int* __restrict__ cnt) {
    int e = blockIdx.x * BS + threadIdx.x;
    if (e < E) atomicAdd(&cnt[ei[E + e]], 1);
}

__global__ __launch_bounds__(BS) void bsum_kernel(const int* __restrict__ cnt, int n,
                                                  int* __restrict__ bsum) {
    __shared__ int s[BS];
    int t = threadIdx.x;
    int i = blockIdx.x * BS + t;
    s[t] = (i < n) ? cnt[i] : 0;
    __syncthreads();
    for (int st = BS / 2; st > 0; st >>= 1) {
        if (t < st) s[t] += s[t + st];
        __syncthreads();
    }
    if (t == 0) bsum[blockIdx.x] = s[0];
}

__global__ __launch_bounds__(512) void bscan_kernel(const int* __restrict__ bsum, int nb,
                                                    int* __restrict__ bpre) {
    __shared__ int s[512];
    int t = threadIdx.x;
    int v = (t < nb) ? bsum[t] : 0;
    s[t] = v;
    __syncthreads();
    for (int off = 1; off < 512; off <<= 1) {
        int add = (t >= off) ? s[t - off] : 0;
        __syncthreads();
        s[t] += add;
        __syncthreads();
    }
    if (t < nb) bpre[t] = s[t] - v;  // exclusive
}

__global__ __launch_bounds__(BS) void scan_kernel(const int* __restrict__ cnt, int n,
                                                  const int* __restrict__ bpre,
                                                  int* __restrict__ row_ptr,
                                                  int* __restrict__ cursor) {
    __shared__ int s[BS];
    int t = threadIdx.x;
    int i = blockIdx.x * BS + t;
    int v = (i < n) ? cnt[i] : 0;
    s[t] = v;
    __syncthreads();
    for (int off = 1; off < BS; off <<= 1) {
        int add = (t >= off) ? s[t - off] : 0;
        __syncthreads();
        s[t] += add;
        __syncthreads();
    }
    if (i < n) {
        int r = bpre[blockIdx.x] + s[t] - v;
        row_ptr[i] = r;
        cursor[i] = r;
    }
}

__global__ __launch_bounds__(BS) void scatter_kernel(const int* __restrict__ ei, int E,
                                                     int* __restrict__ cursor,
                                                     int* __restrict__ ssrc,
                                                     int* __restrict__ sdst) {
    int e = blockIdx.x * BS + threadIdx.x;
    if (e < E) {
        int d = ei[E + e];
        int p = atomicAdd(&cursor[d], 1);
        ssrc[p] = ei[e];
        sdst[p] = d;
    }
}

// ---------------- fused edge-MLP + block-segmented max ----------------
// Phase 1: thread k (sorted edge) computes m = relu(concat(feat_src, rel) @ Wa
//          + ba) @ Wb + bb straight-line (no loop-carried arrays -> no spill),
//          writes transposed into LDS sm[ch][tid] (bank-conflict-free).
// Phase 2: (node,channel) pairs across lanes reduce max over the node's edges
//          inside this block. Interior node: plain store of ordenc(max).
//          Straddling node: atomicMax. Buffer pre-initialized to ORD_NEG_INF.

template <int IN_DIM>
__global__ __launch_bounds__(BS) void edge_seg_kernel(
    const float* __restrict__ pos, const int* __restrict__ row_ptr, const int* __restrict__ cnt,
    const int* __restrict__ ssrc, const int* __restrict__ sdst, const float* __restrict__ hfeat,
    const float* __restrict__ Wa, const float* __restrict__ ba, const float* __restrict__ Wb,
    const float* __restrict__ bb, unsigned* __restrict__ agg, int E) {
    __shared__ float sWa[IN_DIM * 32];
    __shared__ float sba[32];
    __shared__ float sWb[32 * 32];
    __shared__ float sbb[32];
    __shared__ float sm[32][BS + 1];  // [channel][edge-slot], +1 pad -> (c+t)%32 banks

    const int tid = threadIdx.x;
    for (int i = tid; i < IN_DIM * 32; i += BS) sWa[i] = Wa[i];
    for (int i = tid; i < 32 * 32; i += BS) sWb[i] = Wb[i];
    if (tid < 32) {
        sba[tid] = ba[tid];
        sbb[tid] = bb[tid];
    }
    __syncthreads();

    const int k0 = blockIdx.x * BS;
    const int k = k0 + tid;
    const int blockEnd = min(k0 + BS, E);

    if (k < E) {
        const int src = ssrc[k];
        const int dst = sdst[k];

        const float psx = pos[src * 3 + 0];
        const float psy = pos[src * 3 + 1];
        const float psz = pos[src * 3 + 2];
        const float rx = psx - pos[dst * 3 + 0];
        const float ry = psy - pos[dst * 3 + 1];
        const float rz = psz - pos[dst * 3 + 2];

        float feat[IN_DIM];
        if constexpr (IN_DIM == 6) {
            feat[0] = psx;
            feat[1] = psy;
            feat[2] = psz;
            feat[3] = rx;
            feat[4] = ry;
            feat[5] = rz;
        } else {
            const float4* hp = reinterpret_cast<const float4*>(hfeat + (size_t)src * 32);
#pragma unroll
            for (int q = 0; q < 8; ++q) {
                float4 v = hp[q];
                feat[q * 4 + 0] = v.x;
                feat[q * 4 + 1] = v.y;
                feat[q * 4 + 2] = v.z;
                feat[q * 4 + 3] = v.w;
            }
            feat[32] = rx;
            feat[33] = ry;
            feat[34] = rz;
        }

        float hid[32];
#pragma unroll
        for (int f4 = 0; f4 < 8; ++f4) {
            float4 a = *reinterpret_cast<const float4*>(&sba[f4 * 4]);
#pragma unroll
            for (int i = 0; i < IN_DIM; ++i) {
                float4 w = *reinterpret_cast<const float4*>(&sWa[i * 32 + f4 * 4]);
                a.x = fmaf(feat[i], w.x, a.x);
                a.y = fmaf(feat[i], w.y, a.y);
                a.z = fmaf(feat[i], w.z, a.z);
                a.w = fmaf(feat[i], w.w, a.w);
            }
            hid[f4 * 4 + 0] = fmaxf(a.x, 0.0f);
            hid[f4 * 4 + 1] = fmaxf(a.y, 0.0f);
            hid[f4 * 4 + 2] = fmaxf(a.z, 0.0f);
            hid[f4 * 4 + 3] = fmaxf(a.w, 0.0f);
        }

#pragma unroll
        for (int k4 = 0; k4 < 8; ++k4) {
            float4 a = *reinterpret_cast<const float4*>(&sbb[k4 * 4]);
#pragma unroll
            for (int h = 0; h < 32; ++h) {
                float4 w = *reinterpret_cast<const float4*>(&sWb[h * 32 + k4 * 4]);
                a.x = fmaf(hid[h], w.x, a.x);
                a.y = fmaf(hid[h], w.y, a.y);
                a.z = fmaf(hid[h], w.z, a.z);
                a.w = fmaf(hid[h], w.w, a.w);
            }
            sm[k4 * 4 + 0][tid] = a.x;
            sm[k4 * 4 + 1][tid] = a.y;
            sm[k4 * 4 + 2][tid] = a.z;
            sm[k4 * 4 + 3][tid] = a.w;
        }
    } else {
#pragma unroll
        for (int c = 0; c < 32; ++c) sm[c][tid] = -INFINITY;
    }
    __syncthreads();

    // phase 2: segmented max over nodes covered by this block
    const int d0 = sdst[k0];
    const int d1 = sdst[blockEnd - 1];
    const int nPairs = (d1 - d0 + 1) * 32;
    for (int idx = tid; idx < nPairs; idx += BS) {
        const int c = idx & 31;
        const int n = d0 + (idx >> 5);
        const int rs = row_ptr[n];
        const int re = rs + cnt[n];
        const int s0 = max(rs, k0);
        const int s1 = min(re, blockEnd);
        if (s0 >= s1) continue;  // deg-0 node inside [d0,d1]
        float v = -INFINITY;
        for (int e = s0; e < s1; ++e) v = fmaxf(v, sm[c][e - k0]);
        unsigned* p = &agg[(size_t)n * 32 + c];
        const unsigned enc = ordenc(v);
        if (rs >= k0 && re <= blockEnd)
            *p = enc;  // node fully inside this block
        else
            atomicMax(p, enc);  // straddles block boundary
    }
}

extern "C" void kernel_launch(void* const* d_in, const int* in_sizes, int n_in,
                              void* d_out, int out_size, void* d_ws, size_t ws_size,
                              hipStream_t stream) {
    const float* pos = (const float*)d_in[0];
    const int* ei = (const int*)d_in[1];
    const float* W1 = (const float*)d_in[3];
    const float* b1 = (const float*)d_in[4];
    const float* W2 = (const float*)d_in[5];
    const float* b2 = (const float*)d_in[6];
    const float* W3 = (const float*)d_in[7];
    const float* b3 = (const float*)d_in[8];
    const float* W4 = (const float*)d_in[9];
    const float* b4 = (const float*)d_in[10];

    const int E = in_sizes[1] / 2;
    const int N = in_sizes[0] / 3;
    const int n32 = N * 32;
    const int NPAD = ((N + BS - 1) / BS) * BS;
    const int NB = (N + BS - 1) / BS;  // <= 512
    const int EB = (E + BS - 1) / BS;

    int* cnt = (int*)d_ws;         // NPAD
    int* row_ptr = cnt + NPAD;     // NPAD
    int* cursor = row_ptr + NPAD;  // NPAD
    int* bsum = cursor + NPAD;     // 512
    int* bpre = bsum + 512;        // 512
    int* ssrc = bpre + 512;        // E
    int* sdst = ssrc + E;          // E
    unsigned* aggA = (unsigned*)(sdst + E);  // N*32: layer-1 agg -> (in place) h1
    unsigned* aggB = (unsigned*)d_out;       // layer-2 agg -> (in place) output

    const int gridN32 = (n32 + BS - 1) / BS;

    // CSR build (shared by both layers)
    zero_kernel<<<NB, BS, 0, stream>>>(cnt, N);
    hist_kernel<<<EB, BS, 0, stream>>>(ei, E, cnt);
    bsum_kernel<<<NB, BS, 0, stream>>>(cnt, N, bsum);
    bscan_kernel<<<1, 512, 0, stream>>>(bsum, NB, bpre);
    scan_kernel<<<NB, BS, 0, stream>>>(cnt, N, bpre, row_ptr, cursor);
    scatter_kernel<<<EB, BS, 0, stream>>>(ei, E, cursor, ssrc, sdst);

    init_agg_kernel<<<gridN32, BS, 0, stream>>>(aggA, aggB, n32);

    edge_seg_kernel<6><<<EB, BS, 0, stream>>>(pos, row_ptr, cnt, ssrc, sdst, nullptr, W1, b1,
                                              W2, b2, aggA, E);
    finalize_kernel<<<gridN32, BS, 0, stream>>>(aggA, n32);  // -> h1 floats

    edge_seg_kernel<35><<<EB, BS, 0, stream>>>(pos, row_ptr, cnt, ssrc, sdst, (const float*)aggA,
                                               W3, b3, W4, b4, aggB, E);
    finalize_kernel<<<gridN32, BS, 0, stream>>>(aggB, n32);
}

// Round 4
// 378.413 us; speedup vs baseline: 36.3158x; 1.7061x over previous
//
#include <hip/hip_runtime.h>
#include <stdint.h>

// PointNet EdgeConv, 2 layers. Round 4.
// R1: scatter atomics bound (1.6 GB memory-side writes).      4209 us
// R2: gather-per-node spilled (VGPR 256, 9.6 GB scratch).    13742 us
// R3: sorted CSR + block-segmented max in LDS.                 646 us
// R4: (a) weights via uniform scalar loads from global (no LDS weights, no
//         divergent guard) -> LDS pipe freed, occupancy 31.8% -> ~50%;
//     (b) phase-2 max reduction unrolled 4-wide (kill serial ds_read chain);
//     (c) scatter without atomics (rank captured in histogram) + int2 edge
//         records to halve scattered store transactions.

#define BS 256

__device__ __forceinline__ unsigned ordenc(float f) {
    unsigned u = __float_as_uint(f);
    return (u & 0x80000000u) ? ~u : (u | 0x80000000u);
}
__device__ __forceinline__ float orddec(unsigned o) {
    unsigned u = (o & 0x80000000u) ? (o ^ 0x80000000u) : ~o;
    return __uint_as_float(u);
}
#define ORD_NEG_INF 0x007FFFFFu  // ordenc(-inf)

// ---------------- small utility kernels ----------------

__global__ __launch_bounds__(BS) void init_agg_kernel(unsigned* __restrict__ a,
                                                      unsigned* __restrict__ b, int n) {
    int i = blockIdx.x * BS + threadIdx.x;
    if (i < n) {
        a[i] = ORD_NEG_INF;
        b[i] = ORD_NEG_INF;
    }
}

__global__ __launch_bounds__(BS) void finalize_kernel(unsigned* __restrict__ buf, int n) {
    int i = blockIdx.x * BS + threadIdx.x;
    if (i < n) {
        float v = orddec(buf[i]);
        reinterpret_cast<float*>(buf)[i] = fmaxf(v, 0.0f);
    }
}

// ---------------- counting sort (CSR build) ----------------

__global__ __launch_bounds__(BS) void zero_kernel(int* __restrict__ p, int n) {
    int i = blockIdx.x * BS + threadIdx.x;
    if (i < n) p[i] = 0;
}

// histogram + per-edge rank within its dst bucket
__global__ __launch_bounds__(BS) void hist_rank_kernel(const int* __restrict__ ei, int E,
                                                       int* __restrict__ cnt,
                                                       int* __restrict__ rank) {
    int e = blockIdx.x * BS + threadIdx.x;
    if (e < E) rank[e] = atomicAdd(&cnt[ei[E + e]], 1);
}

__global__ __launch_bounds__(BS) void bsum_kernel(const int* __restrict__ cnt, int n,
                                                  int* __restrict__ bsum) {
    __shared__ int s[BS];
    int t = threadIdx.x;
    int i = blockIdx.x * BS + t;
    s[t] = (i < n) ? cnt[i] : 0;
    __syncthreads();
    for (int st = BS / 2; st > 0; st >>= 1) {
        if (t < st) s[t] += s[t + st];
        __syncthreads();
    }
    if (t == 0) bsum[blockIdx.x] = s[0];
}

__global__ __launch_bounds__(512) void bscan_kernel(const int* __restrict__ bsum, int nb,
                                                    int* __restrict__ bpre) {
    __shared__ int s[512];
    int t = threadIdx.x;
    int v = (t < nb) ? bsum[t] : 0;
    s[t] = v;
    __syncthreads();
    for (int off = 1; off < 512; off <<= 1) {
        int add = (t >= off) ? s[t - off] : 0;
        __syncthreads();
        s[t] += add;
        __syncthreads();
    }
    if (t < nb) bpre[t] = s[t] - v;  // exclusive
}

__global__ __launch_bounds__(BS) void scan_kernel(const int* __restrict__ cnt, int n,
                                                  const int* __restrict__ bpre,
                                                  int* __restrict__ row_ptr) {
    __shared__ int s[BS];
    int t = threadIdx.x;
    int i = blockIdx.x * BS + t;
    int v = (i < n) ? cnt[i] : 0;
    s[t] = v;
    __syncthreads();
    for (int off = 1; off < BS; off <<= 1) {
        int add = (t >= off) ? s[t - off] : 0;
        __syncthreads();
        s[t] += add;
        __syncthreads();
    }
    if (i < n) row_ptr[i] = bpre[blockIdx.x] + s[t] - v;
}

// atomic-free scatter: position = row_ptr[dst] + rank[e]; one int2 store
__global__ __launch_bounds__(BS) void scatter_kernel(const int* __restrict__ ei, int E,
                                                     const int* __restrict__ row_ptr,
                                                     const int* __restrict__ rank,
                                                     int2* __restrict__ sedge) {
    int e = blockIdx.x * BS + threadIdx.x;
    if (e < E) {
        int d = ei[E + e];
        int p = row_ptr[d] + rank[e];
        sedge[p] = make_int2(ei[e], d);
    }
}

// ---------------- fused edge-MLP + block-segmented max ----------------
// Weights read straight from global with uniform addresses (scalar loads).
// No divergent guard: k clamped; out-of-range slots are never read in phase 2.

template <int IN_DIM>
__global__ __launch_bounds__(BS, 4) void edge_seg_kernel(
    const float* __restrict__ pos, const int* __restrict__ row_ptr, const int* __restrict__ cnt,
    const int2* __restrict__ sedge, const float* __restrict__ hfeat,
    const float* __restrict__ Wa, const float* __restrict__ ba, const float* __restrict__ Wb,
    const float* __restrict__ bb, unsigned* __restrict__ agg, int E) {
    __shared__ float sm[32][BS + 1];  // [channel][edge-slot]

    const int tid = threadIdx.x;
    const int k0 = blockIdx.x * BS;
    const int blockEnd = min(k0 + BS, E);
    const int k = min(k0 + tid, E - 1);  // clamp, no divergence

    const int2 ed = sedge[k];
    const int src = ed.x;
    const int dst = ed.y;

    const float psx = pos[src * 3 + 0];
    const float psy = pos[src * 3 + 1];
    const float psz = pos[src * 3 + 2];
    const float rx = psx - pos[dst * 3 + 0];
    const float ry = psy - pos[dst * 3 + 1];
    const float rz = psz - pos[dst * 3 + 2];

    float feat[IN_DIM];
    if constexpr (IN_DIM == 6) {
        feat[0] = psx;
        feat[1] = psy;
        feat[2] = psz;
        feat[3] = rx;
        feat[4] = ry;
        feat[5] = rz;
    } else {
        const float4* hp = reinterpret_cast<const float4*>(hfeat + (size_t)src * 32);
#pragma unroll
        for (int q = 0; q < 8; ++q) {
            float4 v = hp[q];
            feat[q * 4 + 0] = v.x;
            feat[q * 4 + 1] = v.y;
            feat[q * 4 + 2] = v.z;
            feat[q * 4 + 3] = v.w;
        }
        feat[32] = rx;
        feat[33] = ry;
        feat[34] = rz;
    }

    // hidden = relu(feat @ Wa + ba)   -- Wa/ba: uniform scalar loads
    float hid[32];
#pragma unroll
    for (int f4 = 0; f4 < 8; ++f4) {
        float4 a = *reinterpret_cast<const float4*>(&ba[f4 * 4]);
#pragma unroll
        for (int i = 0; i < IN_DIM; ++i) {
            float4 w = *reinterpret_cast<const float4*>(&Wa[i * 32 + f4 * 4]);
            a.x = fmaf(feat[i], w.x, a.x);
            a.y = fmaf(feat[i], w.y, a.y);
            a.z = fmaf(feat[i], w.z, a.z);
            a.w = fmaf(feat[i], w.w, a.w);
        }
        hid[f4 * 4 + 0] = fmaxf(a.x, 0.0f);
        hid[f4 * 4 + 1] = fmaxf(a.y, 0.0f);
        hid[f4 * 4 + 2] = fmaxf(a.z, 0.0f);
        hid[f4 * 4 + 3] = fmaxf(a.w, 0.0f);
    }

    // m = hidden @ Wb + bb -> sm transposed
#pragma unroll
    for (int k4 = 0; k4 < 8; ++k4) {
        float4 a = *reinterpret_cast<const float4*>(&bb[k4 * 4]);
#pragma unroll
        for (int h = 0; h < 32; ++h) {
            float4 w = *reinterpret_cast<const float4*>(&Wb[h * 32 + k4 * 4]);
            a.x = fmaf(hid[h], w.x, a.x);
            a.y = fmaf(hid[h], w.y, a.y);
            a.z = fmaf(hid[h], w.z, a.z);
            a.w = fmaf(hid[h], w.w, a.w);
        }
        sm[k4 * 4 + 0][tid] = a.x;
        sm[k4 * 4 + 1][tid] = a.y;
        sm[k4 * 4 + 2][tid] = a.z;
        sm[k4 * 4 + 3][tid] = a.w;
    }
    __syncthreads();

    // phase 2: segmented max over nodes covered by this block (4-wide ILP)
    const int d0 = sedge[k0].y;
    const int d1 = sedge[blockEnd - 1].y;
    const int nPairs = (d1 - d0 + 1) * 32;
    for (int idx = tid; idx < nPairs; idx += BS) {
        const int c = idx & 31;
        const int n = d0 + (idx >> 5);
        const int rs = row_ptr[n];
        const int re = rs + cnt[n];
        const int s0 = max(rs, k0);
        const int s1 = min(re, blockEnd);
        if (s0 >= s1) continue;
        float v0 = -INFINITY, v1 = -INFINITY, v2 = -INFINITY, v3 = -INFINITY;
        int e = s0;
        for (; e + 4 <= s1; e += 4) {
            float a0 = sm[c][e - k0 + 0];
            float a1 = sm[c][e - k0 + 1];
            float a2 = sm[c][e - k0 + 2];
            float a3 = sm[c][e - k0 + 3];
            v0 = fmaxf(v0, a0);
            v1 = fmaxf(v1, a1);
            v2 = fmaxf(v2, a2);
            v3 = fmaxf(v3, a3);
        }
        for (; e < s1; ++e) v0 = fmaxf(v0, sm[c][e - k0]);
        const float v = fmaxf(fmaxf(v0, v1), fmaxf(v2, v3));
        unsigned* p = &agg[(size_t)n * 32 + c];
        const unsigned enc = ordenc(v);
        if (rs >= k0 && re <= blockEnd)
            *p = enc;  // node fully inside this block
        else
            atomicMax(p, enc);  // straddles block boundary
    }
}

extern "C" void kernel_launch(void* const* d_in, const int* in_sizes, int n_in,
                              void* d_out, int out_size, void* d_ws, size_t ws_size,
                              hipStream_t stream) {
    const float* pos = (const float*)d_in[0];
    const int* ei = (const int*)d_in[1];
    const float* W1 = (const float*)d_in[3];
    const float* b1 = (const float*)d_in[4];
    const float* W2 = (const float*)d_in[5];
    const float* b2 = (const float*)d_in[6];
    const float* W3 = (const float*)d_in[7];
    const float* b3 = (const float*)d_in[8];
    const float* W4 = (const float*)d_in[9];
    const float* b4 = (const float*)d_in[10];

    const int E = in_sizes[1] / 2;
    const int N = in_sizes[0] / 3;
    const int n32 = N * 32;
    const int E4 = ((E + 3) / 4) * 4;
    const int NPAD = ((N + BS - 1) / BS) * BS;
    const int NB = (N + BS - 1) / BS;  // <= 512
    const int EB = (E + BS - 1) / BS;

    int* cnt = (int*)d_ws;           // NPAD
    int* row_ptr = cnt + NPAD;       // NPAD
    int* rank = row_ptr + NPAD;      // E4
    int2* sedge = (int2*)(rank + E4);  // E (8B each, 8B-aligned)
    int* bsum = (int*)(sedge + E4);  // 512
    int* bpre = bsum + 512;          // 512
    unsigned* aggA = (unsigned*)(bpre + 512);  // N*32: layer-1 agg -> h1 (16B-aligned)
    unsigned* aggB = (unsigned*)d_out;         // layer-2 agg -> final output

    const int gridN32 = (n32 + BS - 1) / BS;

    // CSR build (shared by both layers)
    zero_kernel<<<NB, BS, 0, stream>>>(cnt, N);
    hist_rank_kernel<<<EB, BS, 0, stream>>>(ei, E, cnt, rank);
    bsum_kernel<<<NB, BS, 0, stream>>>(cnt, N, bsum);
    bscan_kernel<<<1, 512, 0, stream>>>(bsum, NB, bpre);
    scan_kernel<<<NB, BS, 0, stream>>>(cnt, N, bpre, row_ptr);
    scatter_kernel<<<EB, BS, 0, stream>>>(ei, E, row_ptr, rank, sedge);

    init_agg_kernel<<<gridN32, BS, 0, stream>>>(aggA, aggB, n32);

    edge_seg_kernel<6><<<EB, BS, 0, stream>>>(pos, row_ptr, cnt, sedge, nullptr, W1, b1, W2,
                                              b2, aggA, E);
    finalize_kernel<<<gridN32, BS, 0, stream>>>(aggA, n32);  // -> h1 floats

    edge_seg_kernel<35><<<EB, BS, 0, stream>>>(pos, row_ptr, cnt, sedge, (const float*)aggA,
                                               W3, b3, W4, b4, aggB, E);
    finalize_kernel<<<gridN32, BS, 0, stream>>>(aggB, n32);
}

// Round 5
// 337.366 us; speedup vs baseline: 40.7344x; 1.1217x over previous
//
#include <hip/hip_runtime.h>
#include <stdint.h>

// PointNet EdgeConv, 2 layers. Round 5.
// R1: scatter atomics bound (1.6 GB memory-side writes).      4209 us
// R2: gather-per-node spilled (VGPR 256, 9.6 GB scratch).    13742 us
// R3: sorted CSR + block-segmented max in LDS.                 646 us
// R4: scalar-pipe weights, no LDS weights, atomic-free sort.   378 us
// R5: packed fp32 (v_pk_fma_f32 via <2 x float>) halves VALU FMA issue;
//     sm flipped to [edge][33] so phase-1 writes are 8x ds_write_b128;
//     zero+init merged.

#define BS 256

typedef float v2f __attribute__((ext_vector_type(2)));

__device__ __forceinline__ unsigned ordenc(float f) {
    unsigned u = __float_as_uint(f);
    return (u & 0x80000000u) ? ~u : (u | 0x80000000u);
}
__device__ __forceinline__ float orddec(unsigned o) {
    unsigned u = (o & 0x80000000u) ? (o ^ 0x80000000u) : ~o;
    return __uint_as_float(u);
}
#define ORD_NEG_INF 0x007FFFFFu  // ordenc(-inf)

// ---------------- utility kernels ----------------

// zero cnt (i < N) and init both agg buffers (i < n32)
__global__ __launch_bounds__(BS) void init_kernel(int* __restrict__ cnt, int N,
                                                  unsigned* __restrict__ a,
                                                  unsigned* __restrict__ b, int n32) {
    int i = blockIdx.x * BS + threadIdx.x;
    if (i < N) cnt[i] = 0;
    if (i < n32) {
        a[i] = ORD_NEG_INF;
        b[i] = ORD_NEG_INF;
    }
}

__global__ __launch_bounds__(BS) void finalize_kernel(unsigned* __restrict__ buf, int n) {
    int i = blockIdx.x * BS + threadIdx.x;
    if (i < n) {
        float v = orddec(buf[i]);
        reinterpret_cast<float*>(buf)[i] = fmaxf(v, 0.0f);
    }
}

// ---------------- counting sort (CSR build) ----------------

__global__ __launch_bounds__(BS) void hist_rank_kernel(const int* __restrict__ ei, int E,
                                                       int* __restrict__ cnt,
                                                       int* __restrict__ rank) {
    int e = blockIdx.x * BS + threadIdx.x;
    if (e < E) rank[e] = atomicAdd(&cnt[ei[E + e]], 1);
}

__global__ __launch_bounds__(BS) void bsum_kernel(const int* __restrict__ cnt, int n,
                                                  int* __restrict__ bsum) {
    __shared__ int s[BS];
    int t = threadIdx.x;
    int i = blockIdx.x * BS + t;
    s[t] = (i < n) ? cnt[i] : 0;
    __syncthreads();
    for (int st = BS / 2; st > 0; st >>= 1) {
        if (t < st) s[t] += s[t + st];
        __syncthreads();
    }
    if (t == 0) bsum[blockIdx.x] = s[0];
}

__global__ __launch_bounds__(512) void bscan_kernel(const int* __restrict__ bsum, int nb,
                                                    int* __restrict__ bpre) {
    __shared__ int s[512];
    int t = threadIdx.x;
    int v = (t < nb) ? bsum[t] : 0;
    s[t] = v;
    __syncthreads();
    for (int off = 1; off < 512; off <<= 1) {
        int add = (t >= off) ? s[t - off] : 0;
        __syncthreads();
        s[t] += add;
        __syncthreads();
    }
    if (t < nb) bpre[t] = s[t] - v;  // exclusive
}

__global__ __launch_bounds__(BS) void scan_kernel(const int* __restrict__ cnt, int n,
                                                  const int* __restrict__ bpre,
                                                  int* __restrict__ row_ptr) {
    __shared__ int s[BS];
    int t = threadIdx.x;
    int i = blockIdx.x * BS + t;
    int v = (i < n) ? cnt[i] : 0;
    s[t] = v;
    __syncthreads();
    for (int off = 1; off < BS; off <<= 1) {
        int add = (t >= off) ? s[t - off] : 0;
        __syncthreads();
        s[t] += add;
        __syncthreads();
    }
    if (i < n) row_ptr[i] = bpre[blockIdx.x] + s[t] - v;
}

__global__ __launch_bounds__(BS) void scatter_kernel(const int* __restrict__ ei, int E,
                                                     const int* __restrict__ row_ptr,
                                                     const int* __restrict__ rank,
                                                     int2* __restrict__ sedge) {
    int e = blockIdx.x * BS + threadIdx.x;
    if (e < E) {
        int d = ei[E + e];
        int p = row_ptr[d] + rank[e];
        sedge[p] = make_int2(ei[e], d);
    }
}

// ---------------- fused edge-MLP + block-segmented max ----------------

template <int IN_DIM>
__global__ __launch_bounds__(BS, 4) void edge_seg_kernel(
    const float* __restrict__ pos, const int* __restrict__ row_ptr, const int* __restrict__ cnt,
    const int2* __restrict__ sedge, const float* __restrict__ hfeat,
    const float* __restrict__ Wa, const float* __restrict__ ba, const float* __restrict__ Wb,
    const float* __restrict__ bb, unsigned* __restrict__ agg, int E) {
    __shared__ float sm[BS][33];  // [edge-slot][channel], +1 pad

    const int tid = threadIdx.x;
    const int k0 = blockIdx.x * BS;
    const int blockEnd = min(k0 + BS, E);
    const int k = min(k0 + tid, E - 1);  // clamp, no divergence

    const int2 ed = sedge[k];
    const int src = ed.x;
    const int dst = ed.y;

    const float psx = pos[src * 3 + 0];
    const float psy = pos[src * 3 + 1];
    const float psz = pos[src * 3 + 2];
    const float rx = psx - pos[dst * 3 + 0];
    const float ry = psy - pos[dst * 3 + 1];
    const float rz = psz - pos[dst * 3 + 2];

    float feat[IN_DIM];
    if constexpr (IN_DIM == 6) {
        feat[0] = psx;
        feat[1] = psy;
        feat[2] = psz;
        feat[3] = rx;
        feat[4] = ry;
        feat[5] = rz;
    } else {
        const float4* hp = reinterpret_cast<const float4*>(hfeat + (size_t)src * 32);
#pragma unroll
        for (int q = 0; q < 8; ++q) {
            float4 v = hp[q];
            feat[q * 4 + 0] = v.x;
            feat[q * 4 + 1] = v.y;
            feat[q * 4 + 2] = v.z;
            feat[q * 4 + 3] = v.w;
        }
        feat[32] = rx;
        feat[33] = ry;
        feat[34] = rz;
    }

    // hidden = relu(feat @ Wa + ba) -- packed 2xf32 FMA, weights on scalar pipe
    float hid[32];
#pragma unroll
    for (int g = 0; g < 8; ++g) {
        const float4 b4 = *reinterpret_cast<const float4*>(&ba[g * 4]);
        v2f a0 = {b4.x, b4.y};
        v2f a1 = {b4.z, b4.w};
#pragma unroll
        for (int i = 0; i < IN_DIM; ++i) {
            const float4 w4 = *reinterpret_cast<const float4*>(&Wa[i * 32 + g * 4]);
            const v2f f = {feat[i], feat[i]};
            const v2f w0 = {w4.x, w4.y};
            const v2f w1 = {w4.z, w4.w};
            a0 = __builtin_elementwise_fma(f, w0, a0);
            a1 = __builtin_elementwise_fma(f, w1, a1);
        }
        const v2f z = {0.0f, 0.0f};
        a0 = __builtin_elementwise_max(a0, z);
        a1 = __builtin_elementwise_max(a1, z);
        hid[g * 4 + 0] = a0.x;
        hid[g * 4 + 1] = a0.y;
        hid[g * 4 + 2] = a1.x;
        hid[g * 4 + 3] = a1.y;
    }

    // m = hidden @ Wb + bb -> sm[tid][*] via float4 stores
#pragma unroll
    for (int g = 0; g < 8; ++g) {
        const float4 b4 = *reinterpret_cast<const float4*>(&bb[g * 4]);
        v2f a0 = {b4.x, b4.y};
        v2f a1 = {b4.z, b4.w};
#pragma unroll
        for (int h = 0; h < 32; ++h) {
            const float4 w4 = *reinterpret_cast<const float4*>(&Wb[h * 32 + g * 4]);
            const v2f f = {hid[h], hid[h]};
            const v2f w0 = {w4.x, w4.y};
            const v2f w1 = {w4.z, w4.w};
            a0 = __builtin_elementwise_fma(f, w0, a0);
            a1 = __builtin_elementwise_fma(f, w1, a1);
        }
        float4 o;
        o.x = a0.x;
        o.y = a0.y;
        o.z = a1.x;
        o.w = a1.y;
        *reinterpret_cast<float4*>(&sm[tid][g * 4]) = o;
    }
    __syncthreads();

    // phase 2: segmented max over nodes covered by this block (4-wide ILP)
    const int d0 = sedge[k0].y;
    const int d1 = sedge[blockEnd - 1].y;
    const int nPairs = (d1 - d0 + 1) * 32;
    for (int idx = tid; idx < nPairs; idx += BS) {
        const int c = idx & 31;
        const int n = d0 + (idx >> 5);
        const int rs = row_ptr[n];
        const int re = rs + cnt[n];
        const int s0 = max(rs, k0);
        const int s1 = min(re, blockEnd);
        if (s0 >= s1) continue;
        float v0 = -INFINITY, v1 = -INFINITY, v2 = -INFINITY, v3 = -INFINITY;
        int e = s0;
        for (; e + 4 <= s1; e += 4) {
            float a0 = sm[e - k0 + 0][c];
            float a1 = sm[e - k0 + 1][c];
            float a2 = sm[e - k0 + 2][c];
            float a3 = sm[e - k0 + 3][c];
            v0 = fmaxf(v0, a0);
            v1 = fmaxf(v1, a1);
            v2 = fmaxf(v2, a2);
            v3 = fmaxf(v3, a3);
        }
        for (; e < s1; ++e) v0 = fmaxf(v0, sm[e - k0][c]);
        const float v = fmaxf(fmaxf(v0, v1), fmaxf(v2, v3));
        unsigned* p = &agg[(size_t)n * 32 + c];
        const unsigned enc = ordenc(v);
        if (rs >= k0 && re <= blockEnd)
            *p = enc;  // node fully inside this block
        else
            atomicMax(p, enc);  // straddles block boundary
    }
}

extern "C" void kernel_launch(void* const* d_in, const int* in_sizes, int n_in,
                              void* d_out, int out_size, void* d_ws, size_t ws_size,
                              hipStream_t stream) {
    const float* pos = (const float*)d_in[0];
    const int* ei = (const int*)d_in[1];
    const float* W1 = (const float*)d_in[3];
    const float* b1 = (const float*)d_in[4];
    const float* W2 = (const float*)d_in[5];
    const float* b2 = (const float*)d_in[6];
    const float* W3 = (const float*)d_in[7];
    const float* b3 = (const float*)d_in[8];
    const float* W4 = (const float*)d_in[9];
    const float* b4 = (const float*)d_in[10];

    const int E = in_sizes[1] / 2;
    const int N = in_sizes[0] / 3;
    const int n32 = N * 32;
    const int E4 = ((E + 3) / 4) * 4;
    const int NPAD = ((N + BS - 1) / BS) * BS;
    const int NB = (N + BS - 1) / BS;  // <= 512
    const int EB = (E + BS - 1) / BS;

    int* cnt = (int*)d_ws;             // NPAD
    int* row_ptr = cnt + NPAD;         // NPAD
    int* rank = row_ptr + NPAD;        // E4
    int2* sedge = (int2*)(rank + E4);  // E (8B each)
    int* bsum = (int*)(sedge + E4);    // 512
    int* bpre = bsum + 512;            // 512
    unsigned* aggA = (unsigned*)(bpre + 512);  // N*32: layer-1 agg -> h1
    unsigned* aggB = (unsigned*)d_out;         // layer-2 agg -> final output

    const int gridN32 = (n32 + BS - 1) / BS;

    // CSR build (shared by both layers)
    init_kernel<<<gridN32, BS, 0, stream>>>(cnt, N, aggA, aggB, n32);
    hist_rank_kernel<<<EB, BS, 0, stream>>>(ei, E, cnt, rank);
    bsum_kernel<<<NB, BS, 0, stream>>>(cnt, N, bsum);
    bscan_kernel<<<1, 512, 0, stream>>>(bsum, NB, bpre);
    scan_kernel<<<NB, BS, 0, stream>>>(cnt, N, bpre, row_ptr);
    scatter_kernel<<<EB, BS, 0, stream>>>(ei, E, row_ptr, rank, sedge);

    edge_seg_kernel<6><<<EB, BS, 0, stream>>>(pos, row_ptr, cnt, sedge, nullptr, W1, b1, W2,
                                              b2, aggA, E);
    finalize_kernel<<<gridN32, BS, 0, stream>>>(aggA, n32);  // -> h1 floats

    edge_seg_kernel<35><<<EB, BS, 0, stream>>>(pos, row_ptr, cnt, sedge, (const float*)aggA,
                                               W3, b3, W4, b4, aggB, E);
    finalize_kernel<<<gridN32, BS, 0, stream>>>(aggB, n32);
}